// Round 4
// baseline (357.124 us; speedup 1.0000x reference)
//
#include <hip/hip_runtime.h>
#include <hip/hip_bf16.h>

typedef short bf16x8 __attribute__((ext_vector_type(8)));
typedef float f32x4 __attribute__((ext_vector_type(4)));

#define NG   9
#define CIN  1152
#define IG1  128
#define OG1  512
#define IG2  512
#define OG2  128
#define KP   576      // padded K per g2 (9 runs * 64)
#define MT   32       // m-tile per block
#define MTOT 16384
#define HTB  36864    // bytes per ht buffer (32 rows * 72 granules * 16B)
#define OSTRIDE 1156  // epilogue LDS stride (floats)

__device__ __forceinline__ short f2bf(float f) {
    unsigned u = __float_as_uint(f);
    u += 0x7fff + ((u >> 16) & 1);   // RNE
    return (short)(u >> 16);
}
__device__ __forceinline__ short cvt1(float f) {   // HW cvt path (v_cvt_pk_bf16_f32 pairs)
    __hip_bfloat16 h = __float2bfloat16(f);
    return *reinterpret_cast<short*>(&h);
}

// ---- prep (merged): w1 -> bf16 copy; w2 -> permuted+padded bf16 W2p
__global__ __launch_bounds__(256) void prep(const float* __restrict__ w1, const float* __restrict__ w2,
                                            short* __restrict__ w1b, short* __restrict__ w2p) {
    int i = blockIdx.x * 256 + threadIdx.x;
    const int NW1 = NG * OG1 * IG1;            // 589824
    if (i < NW1) { w1b[i] = f2bf(w1[i]); return; }
    int j = i - NW1;
    if (j >= NG * OG2 * KP) return;            // 663552
    int g2  = j / (OG2 * KP);
    int rem = j - g2 * (OG2 * KP);
    int o2  = rem / KP;
    int kp  = rem - o2 * KP;
    int g1 = kp >> 6, r = kp & 63;
    int olo = (512 * g2 - g1 + 8) / 9;         // ceil((512g2-g1)/9)
    int jj = 9 * (olo + r) + g1 - 512 * g2;    // >= 0 by construction
    float v = (jj < 512) ? w2[(g2 * OG2 + o2) * IG2 + jj] : 0.0f;
    w2p[j] = f2bf(v);
}

// ---- fused v2: direct-x L1 -> hardswish -> ht[2] (LDS, dbuf) -> L2 accum -> out
// 512 thr = 8 waves. Wave w: L1 o-slice [w*64,+64); L2 g2=w (128 cols) + g2=8 slice [w*16,+16).
// One barrier per g1 (ht double-buffered). LDS 73984 B -> 2 blocks/CU.
__global__ __launch_bounds__(512, 4) void fused(const float* __restrict__ x,
                                                const short* __restrict__ w1b, const float* __restrict__ b1,
                                                const short* __restrict__ w2p, const float* __restrict__ b2,
                                                float* __restrict__ out) {
    __shared__ __attribute__((aligned(16))) char smem[73984];
    float* outs = (float*)smem;               // epilogue overlay [16][1156] fp32

    const int t = threadIdx.x;
    const int m0 = blockIdx.x * MT;
    const int w = t >> 6, lane = t & 63, lr = lane & 15, lg = lane >> 4;

    // zero both ht buffers once (pad slots must be 0, never rewritten)
    {
        int4 z = {0, 0, 0, 0};
#pragma unroll
        for (int i = 0; i < 9; ++i) *(int4*)(smem + (i * 512 + t) * 16) = z;
    }

    f32x4 acc2[2][8];                          // g2=w, [mi][ni]
    f32x4 acc2b[2];                            // g2=8 slice, [mi]
#pragma unroll
    for (int mi = 0; mi < 2; ++mi) {
#pragma unroll
        for (int ni = 0; ni < 8; ++ni) acc2[mi][ni] = (f32x4){0.f,0.f,0.f,0.f};
        acc2b[mi] = (f32x4){0.f,0.f,0.f,0.f};
    }
    __syncthreads();                           // zeros visible before first ht write

    for (int g1 = 0; g1 < NG; ++g1) {
        char* htb = smem + (g1 & 1) * HTB;

        // ---- L1: swapped MFMA (A=W1 rows o, B=x rows m) -> C[o][m]; x loaded direct (L1$-served)
        f32x4 acc1[4][2];
#pragma unroll
        for (int oi = 0; oi < 4; ++oi)
#pragma unroll
            for (int mi = 0; mi < 2; ++mi) acc1[oi][mi] = (f32x4){0.f,0.f,0.f,0.f};
#pragma unroll
        for (int kf = 0; kf < 4; ++kf) {
            bf16x8 bx[2];
#pragma unroll
            for (int mi = 0; mi < 2; ++mi) {
                const float* p = x + (size_t)(m0 + mi * 16 + lr) * CIN + g1 * IG1 + kf * 32 + lg * 8;
                float4 v0 = *(const float4*)p;
                float4 v1 = *(const float4*)(p + 4);
                bf16x8 s;
                s[0]=cvt1(v0.x); s[1]=cvt1(v0.y); s[2]=cvt1(v0.z); s[3]=cvt1(v0.w);
                s[4]=cvt1(v1.x); s[5]=cvt1(v1.y); s[6]=cvt1(v1.z); s[7]=cvt1(v1.w);
                bx[mi] = s;
            }
#pragma unroll
            for (int oi = 0; oi < 4; ++oi) {
                bf16x8 af = *(const bf16x8*)(w1b + ((size_t)(g1 * OG1 + w * 64 + oi * 16 + lr) * IG1 + kf * 32 + lg * 8));
#pragma unroll
                for (int mi = 0; mi < 2; ++mi)
                    acc1[oi][mi] = __builtin_amdgcn_mfma_f32_16x16x32_bf16(af, bx[mi], acc1[oi][mi], 0, 0, 0);
            }
        }

        // hardswish epilogue -> ht[g1&1] (swizzled b16 scatter; lane holds 4 consecutive o)
#pragma unroll
        for (int oi = 0; oi < 4; ++oi) {
            int ob = w * 64 + oi * 16 + lg * 4;
            float4 bias = *(const float4*)(b1 + g1 * OG1 + ob);
#pragma unroll
            for (int q = 0; q < 4; ++q) {
                int o  = ob + q;
                int c  = 9 * o + g1;
                int g2 = c >> 9;
                int olo = (512 * g2 - g1 + 8) / 9;
                int hc = g2 * 64 + (o - olo);
#pragma unroll
                for (int mi = 0; mi < 2; ++mi) {
                    int m = mi * 16 + lr;
                    float v = acc1[oi][mi][q] + ((const float*)&bias)[q];
                    v = v * fminf(fmaxf(v + 3.0f, 0.0f), 6.0f) * (1.0f / 6.0f);
                    *(short*)(htb + m * 1152 + (((hc >> 3) ^ (m & 7)) << 4) + (hc & 7) * 2) = cvt1(v);
                }
            }
        }
        __syncthreads();   // ht[g1&1] ready; also fences write(g1+1) vs reads(g1-1) of same buffer

        // ---- L2 partial: K-chunk g1*64, disjoint ht reads per wave
#pragma unroll
        for (int kf = 0; kf < 2; ++kf) {
            bf16x8 a_[2], a8_[2];
#pragma unroll
            for (int mi = 0; mi < 2; ++mi) {
                int m = mi * 16 + lr;
                a_[mi]  = *(const bf16x8*)(htb + m * 1152 + (((w * 8 + kf * 4 + lg) ^ (m & 7)) << 4));
                a8_[mi] = *(const bf16x8*)(htb + m * 1152 + (((64 + kf * 4 + lg) ^ (m & 7)) << 4));
            }
#pragma unroll
            for (int ni = 0; ni < 8; ++ni) {
                bf16x8 bfr = *(const bf16x8*)(w2p + (size_t)(w * 128 + ni * 16 + lr) * KP + g1 * 64 + kf * 32 + lg * 8);
#pragma unroll
                for (int mi = 0; mi < 2; ++mi)
                    acc2[mi][ni] = __builtin_amdgcn_mfma_f32_16x16x32_bf16(a_[mi], bfr, acc2[mi][ni], 0, 0, 0);
            }
            bf16x8 b8 = *(const bf16x8*)(w2p + (size_t)(8 * 128 + w * 16 + lr) * KP + g1 * 64 + kf * 32 + lg * 8);
#pragma unroll
            for (int mi = 0; mi < 2; ++mi)
                acc2b[mi] = __builtin_amdgcn_mfma_f32_16x16x32_bf16(a8_[mi], b8, acc2b[mi], 0, 0, 0);
        }
        // no second barrier: next iter's ht-write targets the other buffer
    }

    // ---- output epilogue: 2 half-tiles of 16 rows via LDS, fully-coalesced float4 rows
#pragma unroll
    for (int h = 0; h < 2; ++h) {
        __syncthreads();   // prior ht/outs readers done
#pragma unroll
        for (int ni = 0; ni < 8; ++ni) {
            float bias = b2[w * OG2 + ni * 16 + lr];
            int c = (ni * 16 + lr) * 9 + w;
#pragma unroll
            for (int q = 0; q < 4; ++q)
                outs[(lg * 4 + q) * OSTRIDE + c] = acc2[h][ni][q] + bias;
        }
        {
            float bias8 = b2[8 * OG2 + w * 16 + lr];
            int c8 = (w * 16 + lr) * 9 + 8;
#pragma unroll
            for (int q = 0; q < 4; ++q)
                outs[(lg * 4 + q) * OSTRIDE + c8] = acc2b[h][q] + bias8;
        }
        __syncthreads();
#pragma unroll
        for (int i = 0; i < 9; ++i) {
            int f4 = i * 512 + t;             // 0..4607 float4s = 16 rows x 288
            int row = f4 / 288, c4 = f4 - row * 288;
            float4 v = *(const float4*)&outs[row * OSTRIDE + c4 * 4];
            *(float4*)&out[(size_t)(m0 + h * 16 + row) * CIN + c4 * 4] = v;
        }
    }
}

extern "C" void kernel_launch(void* const* d_in, const int* in_sizes, int n_in,
                              void* d_out, int out_size, void* d_ws, size_t ws_size,
                              hipStream_t stream) {
    const float* x  = (const float*)d_in[0];
    const float* w1 = (const float*)d_in[1];
    const float* b1 = (const float*)d_in[2];
    const float* w2 = (const float*)d_in[3];
    const float* b2 = (const float*)d_in[4];
    float* out = (float*)d_out;

    short* w1b = (short*)d_ws;                                          // 1,179,648 B
    short* w2p = (short*)((char*)d_ws + (size_t)NG * OG1 * IG1 * 2);    // 1,327,104 B

    const int nprep = NG * OG1 * IG1 + NG * OG2 * KP;                   // 1,253,376
    prep<<<(nprep + 255) / 256, 256, 0, stream>>>(w1, w2, w1b, w2p);
    fused<<<MTOT / MT, 512, 0, stream>>>(x, w1b, b1, w2p, b2, out);
}

// Round 5
// 226.073 us; speedup vs baseline: 1.5797x; 1.5797x over previous
//
#include <hip/hip_runtime.h>
#include <hip/hip_bf16.h>

typedef short bf16x8 __attribute__((ext_vector_type(8)));
typedef float f32x4 __attribute__((ext_vector_type(4)));

#define NG   9
#define CIN  1152
#define IG1  128
#define OG1  512
#define IG2  512
#define OG2  128
#define KP   576      // padded K per g2 (9 runs * 64)
#define MT   32       // m-tile per block
#define MTOT 16384
#define HTB  36864    // bytes per ht buffer (32 rows * 72 granules * 16B)
#define OSTRIDE 1156  // epilogue LDS stride (floats)

__device__ __forceinline__ short f2bf(float f) {
    unsigned u = __float_as_uint(f);
    u += 0x7fff + ((u >> 16) & 1);   // RNE
    return (short)(u >> 16);
}
__device__ __forceinline__ short cvt1(float f) {
    __hip_bfloat16 h = __float2bfloat16(f);
    return *reinterpret_cast<short*>(&h);
}

// ---- prep (merged): w1 -> bf16 copy; w2 -> permuted+padded bf16 W2p
__global__ __launch_bounds__(256) void prep(const float* __restrict__ w1, const float* __restrict__ w2,
                                            short* __restrict__ w1b, short* __restrict__ w2p) {
    int i = blockIdx.x * 256 + threadIdx.x;
    const int NW1 = NG * OG1 * IG1;            // 589824
    if (i < NW1) { w1b[i] = f2bf(w1[i]); return; }
    int j = i - NW1;
    if (j >= NG * OG2 * KP) return;            // 663552
    int g2  = j / (OG2 * KP);
    int rem = j - g2 * (OG2 * KP);
    int o2  = rem / KP;
    int kp  = rem - o2 * KP;
    int g1 = kp >> 6, r = kp & 63;
    int olo = (512 * g2 - g1 + 8) / 9;         // ceil((512g2-g1)/9)
    int jj = 9 * (olo + r) + g1 - 512 * g2;    // >= 0 by construction
    float v = (jj < 512) ? w2[(g2 * OG2 + o2) * IG2 + jj] : 0.0f;
    w2p[j] = f2bf(v);
}

// ---- fused v3: direct-x L1 -> hardswish -> ht[2] (LDS dbuf) -> L2 accum -> out
// 512 thr = 8 waves. Wave w: L1 o-slice [w*64,+64); L2 g2=w (128 cols) + g2=8 slice [w*16,+16).
// One RAW barrier per g1 (lgkmcnt-only drain): w2p prefetch stays in flight across it.
__global__ __launch_bounds__(512) void fused(const float* __restrict__ x,
                                             const short* __restrict__ w1b, const float* __restrict__ b1,
                                             const short* __restrict__ w2p, const float* __restrict__ b2,
                                             float* __restrict__ out) {
    __shared__ __attribute__((aligned(16))) char smem[73984];
    float* outs = (float*)smem;               // epilogue overlay [16][1156] fp32

    const int t = threadIdx.x;
    const int m0 = blockIdx.x * MT;
    const int w = t >> 6, lane = t & 63, lr = lane & 15, lg = lane >> 4;

    // zero both ht buffers once (pad slots stay 0 forever; W2p pads are 0 too)
    {
        int4 z = {0, 0, 0, 0};
#pragma unroll
        for (int i = 0; i < 9; ++i) *(int4*)(smem + (i * 512 + t) * 16) = z;
    }

    f32x4 acc2[2][8];                          // g2=w, [mi][ni]
    f32x4 acc2b[2];                            // g2=8 slice, [mi]
#pragma unroll
    for (int mi = 0; mi < 2; ++mi) {
#pragma unroll
        for (int ni = 0; ni < 8; ++ni) acc2[mi][ni] = (f32x4){0.f,0.f,0.f,0.f};
        acc2b[mi] = (f32x4){0.f,0.f,0.f,0.f};
    }

    for (int g1 = 0; g1 < NG; ++g1) {
        char* htb = smem + (g1 & 1) * HTB;

        // ---- A. prefetch ALL w2p fragments for this g1 (consumed after the barrier;
        //         raw barrier below does NOT drain vmcnt, so these stay in flight)
        bf16x8 wf[2][8], wf8[2];
#pragma unroll
        for (int kf = 0; kf < 2; ++kf) {
#pragma unroll
            for (int ni = 0; ni < 8; ++ni)
                wf[kf][ni] = *(const bf16x8*)(w2p + (size_t)(w * 128 + ni * 16 + lr) * KP + g1 * 64 + kf * 32 + lg * 8);
            wf8[kf] = *(const bf16x8*)(w2p + (size_t)(8 * 128 + w * 16 + lr) * KP + g1 * 64 + kf * 32 + lg * 8);
        }

        // ---- B. L1: swapped MFMA (A=W1 rows o, B=x rows m) -> C[o][m]
        f32x4 acc1[4][2];
#pragma unroll
        for (int oi = 0; oi < 4; ++oi)
#pragma unroll
            for (int mi = 0; mi < 2; ++mi) acc1[oi][mi] = (f32x4){0.f,0.f,0.f,0.f};
#pragma unroll
        for (int kf = 0; kf < 4; ++kf) {
            bf16x8 bx[2];
#pragma unroll
            for (int mi = 0; mi < 2; ++mi) {
                const float* p = x + (size_t)(m0 + mi * 16 + lr) * CIN + g1 * IG1 + kf * 32 + lg * 8;
                float4 v0 = *(const float4*)p;
                float4 v1 = *(const float4*)(p + 4);
                bf16x8 s;
                s[0]=cvt1(v0.x); s[1]=cvt1(v0.y); s[2]=cvt1(v0.z); s[3]=cvt1(v0.w);
                s[4]=cvt1(v1.x); s[5]=cvt1(v1.y); s[6]=cvt1(v1.z); s[7]=cvt1(v1.w);
                bx[mi] = s;
            }
#pragma unroll
            for (int oi = 0; oi < 4; ++oi) {
                bf16x8 af = *(const bf16x8*)(w1b + ((size_t)(g1 * OG1 + w * 64 + oi * 16 + lr) * IG1 + kf * 32 + lg * 8));
#pragma unroll
                for (int mi = 0; mi < 2; ++mi)
                    acc1[oi][mi] = __builtin_amdgcn_mfma_f32_16x16x32_bf16(af, bx[mi], acc1[oi][mi], 0, 0, 0);
            }
        }

        // ---- C. hardswish -> ht[g1&1] (swizzled b16 scatter; lane holds 4 consecutive o)
#pragma unroll
        for (int oi = 0; oi < 4; ++oi) {
            int ob = w * 64 + oi * 16 + lg * 4;
            float4 bias = *(const float4*)(b1 + g1 * OG1 + ob);
#pragma unroll
            for (int q = 0; q < 4; ++q) {
                int o  = ob + q;
                int c  = 9 * o + g1;
                int g2 = c >> 9;
                int olo = (512 * g2 - g1 + 8) / 9;
                int hc = g2 * 64 + (o - olo);
#pragma unroll
                for (int mi = 0; mi < 2; ++mi) {
                    int m = mi * 16 + lr;
                    float v = acc1[oi][mi][q] + ((const float*)&bias)[q];
                    v = v * fminf(fmaxf(v + 3.0f, 0.0f), 6.0f) * (1.0f / 6.0f);
                    *(short*)(htb + m * 1152 + (((hc >> 3) ^ (m & 7)) << 4) + (hc & 7) * 2) = cvt1(v);
                }
            }
        }

        // ---- D. LDS-only drain + raw barrier (vmem prefetch NOT drained)
        asm volatile("s_waitcnt lgkmcnt(0)" ::: "memory");
        __builtin_amdgcn_s_barrier();

        // ---- E. L2 partial: ht reads (disjoint per wave) x prefetched w2p
#pragma unroll
        for (int kf = 0; kf < 2; ++kf) {
            bf16x8 a_[2], a8_[2];
#pragma unroll
            for (int mi = 0; mi < 2; ++mi) {
                int m = mi * 16 + lr;
                a_[mi]  = *(const bf16x8*)(htb + m * 1152 + (((w * 8 + kf * 4 + lg) ^ (m & 7)) << 4));
                a8_[mi] = *(const bf16x8*)(htb + m * 1152 + (((64 + kf * 4 + lg) ^ (m & 7)) << 4));
            }
#pragma unroll
            for (int ni = 0; ni < 8; ++ni)
#pragma unroll
                for (int mi = 0; mi < 2; ++mi)
                    acc2[mi][ni] = __builtin_amdgcn_mfma_f32_16x16x32_bf16(a_[mi], wf[kf][ni], acc2[mi][ni], 0, 0, 0);
#pragma unroll
            for (int mi = 0; mi < 2; ++mi)
                acc2b[mi] = __builtin_amdgcn_mfma_f32_16x16x32_bf16(a8_[mi], wf8[kf], acc2b[mi], 0, 0, 0);
        }
        // no second barrier: next iter writes the other ht buffer
    }

    // ---- output epilogue: 2 half-tiles of 16 rows via LDS, fully-coalesced float4 rows
#pragma unroll
    for (int h = 0; h < 2; ++h) {
        __syncthreads();   // prior ht/outs readers done
#pragma unroll
        for (int ni = 0; ni < 8; ++ni) {
            float bias = b2[w * OG2 + ni * 16 + lr];
            int c = (ni * 16 + lr) * 9 + w;
#pragma unroll
            for (int q = 0; q < 4; ++q)
                outs[(lg * 4 + q) * OSTRIDE + c] = acc2[h][ni][q] + bias;
        }
        {
            float bias8 = b2[8 * OG2 + w * 16 + lr];
            int c8 = (w * 16 + lr) * 9 + 8;
#pragma unroll
            for (int q = 0; q < 4; ++q)
                outs[(lg * 4 + q) * OSTRIDE + c8] = acc2b[h][q] + bias8;
        }
        __syncthreads();
#pragma unroll
        for (int i = 0; i < 9; ++i) {
            int f4 = i * 512 + t;             // 0..4607 float4s = 16 rows x 288
            int row = f4 / 288, c4 = f4 - row * 288;
            float4 v = *(const float4*)&outs[row * OSTRIDE + c4 * 4];
            *(float4*)&out[(size_t)(m0 + h * 16 + row) * CIN + c4 * 4] = v;
        }
    }
}

extern "C" void kernel_launch(void* const* d_in, const int* in_sizes, int n_in,
                              void* d_out, int out_size, void* d_ws, size_t ws_size,
                              hipStream_t stream) {
    const float* x  = (const float*)d_in[0];
    const float* w1 = (const float*)d_in[1];
    const float* b1 = (const float*)d_in[2];
    const float* w2 = (const float*)d_in[3];
    const float* b2 = (const float*)d_in[4];
    float* out = (float*)d_out;

    short* w1b = (short*)d_ws;                                          // 1,179,648 B
    short* w2p = (short*)((char*)d_ws + (size_t)NG * OG1 * IG1 * 2);    // 1,327,104 B

    const int nprep = NG * OG1 * IG1 + NG * OG2 * KP;                   // 1,253,376
    prep<<<(nprep + 255) / 256, 256, 0, stream>>>(w1, w2, w1b, w2p);
    fused<<<MTOT / MT, 512, 0, stream>>>(x, w1b, b1, w2p, b2, out);
}